// Round 3
// baseline (231.720 us; speedup 1.0000x reference)
//
#include <hip/hip_runtime.h>

typedef __bf16 bf16;
typedef __bf16 bf16x4 __attribute__((ext_vector_type(4)));
typedef __bf16 bf16x8 __attribute__((ext_vector_type(8)));
typedef float f32x4 __attribute__((ext_vector_type(4)));
typedef float f32x16 __attribute__((ext_vector_type(16)));

#define DIMD 1024
#define NHEAD 16
#define HDIM 64
#define BATCH 2
#define SEQ 2048
#define MTOT (BATCH*SEQ)   // 4096

#define EXP2F(x) __builtin_amdgcn_exp2f(x)

// ---- memory plan (total ws use = 16 MB) ----
// d_out: [0,8MB) Qb bf16 (pre-scaled 0.125*log2e); [8,16MB) Kb   (dead after attn -> out)
// d_ws:  [0,8MB) xb bf16 -> dead after QKV GEMM, then Ob
//        [8,16MB) Vt bf16 -> dead after attn, then wprojb bf16 (2MB)
#define OFF_XB (0ull)
#define OFF_OB (0ull)
#define OFF_VT (8ull<<20)
#define OFF_WP (8ull<<20)

__device__ __forceinline__ void g2l16(const void* g, void* l) {
  __builtin_amdgcn_global_load_lds(
      (const __attribute__((address_space(1))) void*)g,
      (__attribute__((address_space(3))) void*)l,
      16, 0, 0);
}

__device__ __forceinline__ bf16x8 cvt8(float4 a, float4 b) {
  bf16x8 r = { (bf16)a.x, (bf16)a.y, (bf16)a.z, (bf16)a.w,
               (bf16)b.x, (bf16)b.y, (bf16)b.z, (bf16)b.w };
  return r;
}

// ---------------- fp32 -> bf16 conversion ----------------
__global__ __launch_bounds__(256) void cvt_kernel(const float* __restrict__ in,
                                                  bf16* __restrict__ out, int n4) {
  int i = blockIdx.x * blockDim.x + threadIdx.x;
  if (i < n4) {
    float4 v = ((const float4*)in)[i];
    bf16x4 o = { (bf16)v.x, (bf16)v.y, (bf16)v.z, (bf16)v.w };
    ((bf16x4*)out)[i] = o;
  }
}

// ---------------- QKV GEMM (unchanged — R9/R10 proven) ----------------
__global__ __launch_bounds__(256, 3) void gemm_qkv(
    const bf16* __restrict__ A, const float* __restrict__ W,
    const float* __restrict__ bias,
    bf16* __restrict__ Qb, bf16* __restrict__ Kb, bf16* __restrict__ Vt)
{
  __shared__ bf16 lA[2][128 * 32];
  __shared__ bf16 lB[2][128 * 32];
  const int tid = threadIdx.x;
  const int wave = tid >> 6, lane = tid & 63;
  const int l15 = lane & 15, quad = lane >> 4;
  const int wm = wave >> 1, wn = wave & 1;
  const int tm = blockIdx.y * 128, tn = blockIdx.x * 128;

  f32x4 acc[4][4] = {};

  const int srow = tid >> 2, sch = (tid & 3) * 8;
  const bf16*  ga = &A[(size_t)(tm + srow) * DIMD + sch];
  const float* gb = &W[(size_t)(tn + srow) * DIMD + sch];

  g2l16(ga,                     &lA[0][wave * 512]);
  g2l16(ga + (size_t)64 * DIMD, &lA[0][2048 + wave * 512]);
  float4 bv0 = ((const float4*)gb)[0], bv1 = ((const float4*)gb)[1];
  float4 bv2 = ((const float4*)(gb + (size_t)64 * DIMD))[0],
         bv3 = ((const float4*)(gb + (size_t)64 * DIMD))[1];

  for (int kt = 0; kt < 32; kt++) {
    bf16* sB = lB[kt & 1];
    *(bf16x8*)&sB[srow * 32 + sch]        = cvt8(bv0, bv1);
    *(bf16x8*)&sB[(64 + srow) * 32 + sch] = cvt8(bv2, bv3);
    __syncthreads();

    if (kt < 31) {
      const int kn = (kt + 1) * 32;
      bf16* nA = lA[(kt + 1) & 1];
      g2l16(ga + kn,                     &nA[wave * 512]);
      g2l16(ga + kn + (size_t)64 * DIMD, &nA[2048 + wave * 512]);
      const float* gbn = gb + kn;
      bv0 = ((const float4*)gbn)[0]; bv1 = ((const float4*)gbn)[1];
      bv2 = ((const float4*)(gbn + (size_t)64 * DIMD))[0];
      bv3 = ((const float4*)(gbn + (size_t)64 * DIMD))[1];
    }

    const bf16* sA = lA[kt & 1];
    bf16x8 af[4], bfr[4];
#pragma unroll
    for (int i = 0; i < 4; i++)
      af[i] = *(const bf16x8*)&sA[(wm * 64 + i * 16 + l15) * 32 + quad * 8];
#pragma unroll
    for (int i = 0; i < 4; i++)
      bfr[i] = *(const bf16x8*)&sB[(wn * 64 + i * 16 + l15) * 32 + quad * 8];
#pragma unroll
    for (int i = 0; i < 4; i++)
#pragma unroll
      for (int j = 0; j < 4; j++)
        acc[i][j] = __builtin_amdgcn_mfma_f32_16x16x32_bf16(af[i], bfr[j], acc[i][j], 0, 0, 0);
  }

  const int sel = tn >> 10;  // 0=Q 1=K 2=V
#pragma unroll
  for (int j = 0; j < 4; j++) {
    const int n = tn + wn * 64 + j * 16 + l15;
    const float bv = bias[n];
    const int d = n & 1023, h = d >> 6, hd = d & 63;
#pragma unroll
    for (int i = 0; i < 4; i++) {
      const int mbase = tm + wm * 64 + i * 16 + quad * 4;
      const int b = mbase >> 11, s0 = mbase & 2047;
      const int bh = b * NHEAD + h;
      if (sel == 2) {
        bf16x4 vv = { (bf16)(acc[i][j][0] + bv), (bf16)(acc[i][j][1] + bv),
                      (bf16)(acc[i][j][2] + bv), (bf16)(acc[i][j][3] + bv) };
        *(bf16x4*)&Vt[((size_t)bh * HDIM + hd) * SEQ + s0] = vv;
      } else {
#pragma unroll
        for (int r = 0; r < 4; r++) {
          float v = acc[i][j][r] + bv;
          if (sel == 0)
            Qb[((size_t)bh * SEQ + s0 + r) * HDIM + hd] = (bf16)(v * 0.18033688f); // 0.125*log2e
          else
            Kb[((size_t)bh * SEQ + s0 + r) * HDIM + hd] = (bf16)v;
        }
      }
    }
  }
}

// ---------------- proj GEMM v2: both operands async via global_load_lds ----
__global__ __launch_bounds__(256, 2) void gemm_proj(
    const bf16* __restrict__ A, const bf16* __restrict__ Bt,
    const float* __restrict__ bias, float* __restrict__ out)
{
  __shared__ bf16 lA[2][64 * 32];
  __shared__ bf16 lB[2][128 * 32];
  const int tid = threadIdx.x;
  const int wave = tid >> 6, lane = tid & 63;
  const int l15 = lane & 15, quad = lane >> 4;
  const int tm = blockIdx.y * 64, tn = blockIdx.x * 128;

  f32x4 acc[4][2] = {};

  const int srow = tid >> 2, sch = (tid & 3) * 8;
  const bf16* ga = &A[(size_t)(tm + srow) * DIMD + sch];
  const bf16* gb = &Bt[(size_t)(tn + srow) * DIMD + sch];

  g2l16(ga,                     &lA[0][wave * 512]);
  g2l16(gb,                     &lB[0][wave * 512]);
  g2l16(gb + (size_t)64 * DIMD, &lB[0][2048 + wave * 512]);

  for (int kt = 0; kt < 32; kt++) {
    __syncthreads();

    if (kt < 31) {
      const int kn = (kt + 1) * 32;
      bf16* nA = lA[(kt + 1) & 1];
      bf16* nB = lB[(kt + 1) & 1];
      g2l16(ga + kn,                     &nA[wave * 512]);
      g2l16(gb + kn,                     &nB[wave * 512]);
      g2l16(gb + kn + (size_t)64 * DIMD, &nB[2048 + wave * 512]);
    }

    const bf16* sA = lA[kt & 1];
    const bf16* sB = lB[kt & 1];
    bf16x8 af[4], bfr[2];
#pragma unroll
    for (int i = 0; i < 4; i++)
      af[i] = *(const bf16x8*)&sA[(i * 16 + l15) * 32 + quad * 8];
#pragma unroll
    for (int j = 0; j < 2; j++)
      bfr[j] = *(const bf16x8*)&sB[(wave * 32 + j * 16 + l15) * 32 + quad * 8];
#pragma unroll
    for (int i = 0; i < 4; i++)
#pragma unroll
      for (int j = 0; j < 2; j++)
        acc[i][j] = __builtin_amdgcn_mfma_f32_16x16x32_bf16(af[i], bfr[j], acc[i][j], 0, 0, 0);
  }

#pragma unroll
  for (int j = 0; j < 2; j++) {
    const int n = tn + wave * 32 + j * 16 + l15;
    const float bv = bias[n];
#pragma unroll
    for (int i = 0; i < 4; i++) {
      const int mbase = tm + i * 16 + quad * 4;
#pragma unroll
      for (int r = 0; r < 4; r++)
        out[(size_t)(mbase + r) * DIMD + n] = acc[i][j][r] + bv;
    }
  }
}

// ---------------- flash attention v9: KVBLK=128, in-register P ----------------
// Budget from v6/v8 counters (corrected MFMA cost ~33cy/instr): per 64-row iter
// 4470cy wall vs MFMA 1056 + VALU 1630 + DS ~2000 -> ~2000cy stall; v8 proved
// softmax chain is NOT the path. This version restructures the iteration:
//  * 128 K-rows/iter (16 iters): halves softmax bookkeeping + shfl count,
//    doubles MFMA run length and prefetch distance.
//  * P stays in registers: pack to bf16 + __shfl_xor(,32) half-exchange
//    (derived against v6's proven lP layout); removes lP (-18KB) and all
//    P LDS traffic; DS volume -37%.
//  * Race-free schedule: barrier#1 = staging visible, barrier#2 = reads done,
//    then stage tile t+1 (K and V single-buffered; LDS 35,840 B).
#define KTILE 128
#define KSTR 72     // 144B row stride: octet of lanes tiles all 32 banks
#define VSTR 136    // 272B row stride: same property
__global__ __launch_bounds__(256, 2) void attn_kernel(
    const bf16* __restrict__ Qb, const bf16* __restrict__ Kb,
    const bf16* __restrict__ Vt, bf16* __restrict__ Ob)
{
  __shared__ bf16 lK[KTILE * KSTR];   // [k-row 0..127][d 0..63]
  __shared__ bf16 lV[64 * VSTR];      // [hd 0..63][s 0..127]

  const int tid = threadIdx.x;
  const int wave = tid >> 6, lane = tid & 63;
  const int l31 = lane & 31, h = lane >> 5;
  const int xcd = blockIdx.x & 7, grp = blockIdx.x >> 3;
  const int bh = xcd + 8 * (grp & 3);
  const int qt = grp >> 2;

  const int qrow = qt * 128 + wave * 32 + l31;
  const bf16* qp = Qb + ((size_t)bh * SEQ + qrow) * HDIM + h * 8;
  bf16x8 qf[4];
#pragma unroll
  for (int c = 0; c < 4; c++) qf[c] = *(const bf16x8*)(qp + c * 16);

  const int srow = tid >> 3;            // 0..31
  const int sch = (tid & 7) * 8;        // 8-elem (16B) column offset
  const bf16* kg = Kb + ((size_t)bh * SEQ + srow) * HDIM + sch;
  const bf16* vg = Vt + ((size_t)bh * HDIM + srow) * SEQ + sch;

  uint4 kr[4], vr[4];
#pragma unroll
  for (int i = 0; i < 4; i++)
    kr[i] = *(const uint4*)(kg + (size_t)(32 * i) * HDIM);
#pragma unroll
  for (int i = 0; i < 2; i++)
#pragma unroll
    for (int j = 0; j < 2; j++)
      vr[i * 2 + j] = *(const uint4*)(vg + (size_t)(32 * i) * SEQ + j * 64);

  // stage tile 0
#pragma unroll
  for (int i = 0; i < 4; i++)
    *(uint4*)&lK[(srow + 32 * i) * KSTR + sch] = kr[i];
#pragma unroll
  for (int i = 0; i < 2; i++)
#pragma unroll
    for (int j = 0; j < 2; j++)
      *(uint4*)&lV[(srow + 32 * i) * VSTR + j * 64 + sch] = vr[i * 2 + j];

  f32x16 o0 = {}, o1 = {};
  float mrow = -1e30f, lrow = 0.f;

  for (int kt = 0; kt < SEQ / KTILE; kt++) {
    __syncthreads();   // barrier#1: tile kt staged

    if (kt < SEQ / KTILE - 1) {
      const size_t koff = (size_t)(kt + 1) * KTILE;
#pragma unroll
      for (int i = 0; i < 4; i++)
        kr[i] = *(const uint4*)(kg + (koff + 32 * i) * HDIM);
#pragma unroll
      for (int i = 0; i < 2; i++)
#pragma unroll
        for (int j = 0; j < 2; j++)
          vr[i * 2 + j] = *(const uint4*)(vg + (size_t)(32 * i) * SEQ + koff + j * 64);
    }

    // ---- S^T = K Q^T : 4 row-groups of 32 k-rows, K-chunks c ----
    f32x16 s0 = {}, s1 = {}, s2 = {}, s3 = {};
#pragma unroll
    for (int c = 0; c < 4; c++) {
      bf16x8 k0 = *(const bf16x8*)&lK[(l31)       * KSTR + c * 16 + h * 8];
      bf16x8 k1 = *(const bf16x8*)&lK[(32 + l31)  * KSTR + c * 16 + h * 8];
      bf16x8 k2 = *(const bf16x8*)&lK[(64 + l31)  * KSTR + c * 16 + h * 8];
      bf16x8 k3 = *(const bf16x8*)&lK[(96 + l31)  * KSTR + c * 16 + h * 8];
      s0 = __builtin_amdgcn_mfma_f32_32x32x16_bf16(k0, qf[c], s0, 0, 0, 0);
      s1 = __builtin_amdgcn_mfma_f32_32x32x16_bf16(k1, qf[c], s1, 0, 0, 0);
      s2 = __builtin_amdgcn_mfma_f32_32x32x16_bf16(k2, qf[c], s2, 0, 0, 0);
      s3 = __builtin_amdgcn_mfma_f32_32x32x16_bf16(k3, qf[c], s3, 0, 0, 0);
    }

    // ---- softmax over 64 regs (this lane's half of 128 k-rows) ----
    float a[16];
#pragma unroll
    for (int r = 0; r < 16; r++)
      a[r] = fmaxf(fmaxf(s0[r], s1[r]), fmaxf(s2[r], s3[r]));
#pragma unroll
    for (int r = 0; r < 8; r++) a[r] = fmaxf(a[r], a[r + 8]);
#pragma unroll
    for (int r = 0; r < 4; r++) a[r] = fmaxf(a[r], a[r + 4]);
    float mx = fmaxf(fmaxf(a[0], a[1]), fmaxf(a[2], a[3]));
    mx = fmaxf(mx, __shfl_xor(mx, 32, 64));

    const float nm = fmaxf(mrow, mx);
    const float alpha = EXP2F(mrow - nm);
    mrow = nm;

#pragma unroll
    for (int r = 0; r < 16; r++) {
      s0[r] = EXP2F(s0[r] - nm);
      s1[r] = EXP2F(s1[r] - nm);
      s2[r] = EXP2F(s2[r] - nm);
      s3[r] = EXP2F(s3[r] - nm);
    }
#pragma unroll
    for (int r = 0; r < 16; r++)
      a[r] = (s0[r] + s1[r]) + (s2[r] + s3[r]);
#pragma unroll
    for (int r = 0; r < 8; r++) a[r] += a[r + 8];
#pragma unroll
    for (int r = 0; r < 4; r++) a[r] += a[r + 4];
    float rs = (a[0] + a[1]) + (a[2] + a[3]);
    rs += __shfl_xor(rs, 32, 64);
    lrow = lrow * alpha + rs;

#pragma unroll
    for (int r = 0; r < 16; r++) { o0[r] *= alpha; o1[r] *= alpha; }

    // ---- pack P to bf16 + half-exchange, fused with PV ----
    // pf[cc=2g+cp], lane(l31,h) must hold P[cc*16 + 8h + j][l31], j=0..7.
    // j0-3 from h'=0 lane's s{g}[4q..4q+3], j4-7 from h'=1 lane's same regs,
    // q = 2cp + h_dest. Lane sends w[2cp+1-h], receives partner's w[2cp+h].
#pragma unroll
    for (int g = 0; g < 4; g++) {
      const f32x16& sg = (g == 0) ? s0 : (g == 1) ? s1 : (g == 2) ? s2 : s3;
#pragma unroll
      for (int cp = 0; cp < 2; cp++) {
        bf16x4 pk0 = { (bf16)sg[8 * cp + 0], (bf16)sg[8 * cp + 1],
                       (bf16)sg[8 * cp + 2], (bf16)sg[8 * cp + 3] };   // q=2cp
        bf16x4 pk1 = { (bf16)sg[8 * cp + 4], (bf16)sg[8 * cp + 5],
                       (bf16)sg[8 * cp + 6], (bf16)sg[8 * cp + 7] };   // q=2cp+1
        uint2 w0 = *(uint2*)&pk0;
        uint2 w1 = *(uint2*)&pk1;
        unsigned send0 = h ? w0.x : w1.x;
        unsigned send1 = h ? w0.y : w1.y;
        unsigned recv0 = __shfl_xor(send0, 32, 64);
        unsigned recv1 = __shfl_xor(send1, 32, 64);
        union { unsigned u[4]; bf16x8 v; } f;
        f.u[0] = h ? recv0 : w0.x;   // j0j1  (h'=0 source)
        f.u[1] = h ? recv1 : w0.y;   // j2j3
        f.u[2] = h ? w1.x : recv0;   // j4j5  (h'=1 source)
        f.u[3] = h ? w1.y : recv1;   // j6j7
        const int cc = 2 * g + cp;
        bf16x8 v0 = *(const bf16x8*)&lV[(l31)      * VSTR + cc * 16 + h * 8];
        bf16x8 v1 = *(const bf16x8*)&lV[(32 + l31) * VSTR + cc * 16 + h * 8];
        o0 = __builtin_amdgcn_mfma_f32_32x32x16_bf16(v0, f.v, o0, 0, 0, 0);
        o1 = __builtin_amdgcn_mfma_f32_32x32x16_bf16(v1, f.v, o1, 0, 0, 0);
      }
    }

    __syncthreads();   // barrier#2: all lK/lV reads of tile kt complete

    if (kt < SEQ / KTILE - 1) {
#pragma unroll
      for (int i = 0; i < 4; i++)
        *(uint4*)&lK[(srow + 32 * i) * KSTR + sch] = kr[i];
#pragma unroll
      for (int i = 0; i < 2; i++)
#pragma unroll
        for (int j = 0; j < 2; j++)
          *(uint4*)&lV[(srow + 32 * i) * VSTR + j * 64 + sch] = vr[i * 2 + j];
    }
  }

  const int b = bh >> 4, head = bh & 15;
  const float inv = 1.f / lrow;
  const size_t base = ((size_t)b * SEQ + qrow) * DIMD + head * HDIM;
#pragma unroll
  for (int g = 0; g < 4; g++) {
    bf16x4 oa = { (bf16)(o0[4*g] * inv), (bf16)(o0[4*g+1] * inv),
                  (bf16)(o0[4*g+2] * inv), (bf16)(o0[4*g+3] * inv) };
    bf16x4 ob = { (bf16)(o1[4*g] * inv), (bf16)(o1[4*g+1] * inv),
                  (bf16)(o1[4*g+2] * inv), (bf16)(o1[4*g+3] * inv) };
    *(bf16x4*)&Ob[base + g * 8 + h * 4]      = oa;
    *(bf16x4*)&Ob[base + 32 + g * 8 + h * 4] = ob;
  }
}

extern "C" void kernel_launch(void* const* d_in, const int* in_sizes, int n_in,
                              void* d_out, int out_size, void* d_ws, size_t ws_size,
                              hipStream_t stream) {
  const float* x      = (const float*)d_in[0];
  const float* w_qkv  = (const float*)d_in[1];
  const float* b_qkv  = (const float*)d_in[2];
  const float* w_proj = (const float*)d_in[3];
  const float* b_proj = (const float*)d_in[4];
  float* out = (float*)d_out;
  char* ws = (char*)d_ws;

  bf16* Qb = (bf16*)d_out;
  bf16* Kb = (bf16*)d_out + (size_t)MTOT * DIMD;
  bf16* xb     = (bf16*)(ws + OFF_XB);
  bf16* Ob     = (bf16*)(ws + OFF_OB);   // overlays xb (dead after QKV GEMM)
  bf16* Vt     = (bf16*)(ws + OFF_VT);
  bf16* wprojb = (bf16*)(ws + OFF_WP);   // overlays Vt (dead after attn)

  cvt_kernel<<<(MTOT * DIMD / 4) / 256, 256, 0, stream>>>(x, xb, MTOT * DIMD / 4);
  gemm_qkv<<<dim3(24, 32), 256, 0, stream>>>(xb, w_qkv, b_qkv, Qb, Kb, Vt);
  attn_kernel<<<BATCH * NHEAD * (SEQ / 128), 256, 0, stream>>>(Qb, Kb, Vt, Ob);
  cvt_kernel<<<(DIMD * DIMD / 4) / 256, 256, 0, stream>>>(w_proj, wprojb, DIMD * DIMD / 4);
  gemm_proj<<<dim3(8, 64), 256, 0, stream>>>(Ob, wprojb, b_proj, out);
}

// Round 4
// 191.004 us; speedup vs baseline: 1.2132x; 1.2132x over previous
//
#include <hip/hip_runtime.h>

typedef __bf16 bf16;
typedef __bf16 bf16x4 __attribute__((ext_vector_type(4)));
typedef __bf16 bf16x8 __attribute__((ext_vector_type(8)));
typedef float f32x4 __attribute__((ext_vector_type(4)));
typedef float f32x16 __attribute__((ext_vector_type(16)));

#define DIMD 1024
#define NHEAD 16
#define HDIM 64
#define BATCH 2
#define SEQ 2048
#define MTOT (BATCH*SEQ)   // 4096

#define EXP2F(x) __builtin_amdgcn_exp2f(x)

// ---- memory plan (total ws use = 16 MB) ----
// d_out: [0,8MB) Qb bf16 (pre-scaled 0.125*log2e); [8,16MB) Kb   (dead after attn -> out)
// d_ws:  [0,8MB) xb bf16 -> dead after QKV GEMM, then Ob
//        [8,16MB) Vt bf16 -> dead after attn, then wprojb bf16 (2MB)
#define OFF_XB (0ull)
#define OFF_OB (0ull)
#define OFF_VT (8ull<<20)
#define OFF_WP (8ull<<20)

__device__ __forceinline__ void g2l16(const void* g, void* l) {
  __builtin_amdgcn_global_load_lds(
      (const __attribute__((address_space(1))) void*)g,
      (__attribute__((address_space(3))) void*)l,
      16, 0, 0);
}

__device__ __forceinline__ bf16x8 cvt8(float4 a, float4 b) {
  bf16x8 r = { (bf16)a.x, (bf16)a.y, (bf16)a.z, (bf16)a.w,
               (bf16)b.x, (bf16)b.y, (bf16)b.z, (bf16)b.w };
  return r;
}

// ---------------- fp32 -> bf16 conversion ----------------
__global__ __launch_bounds__(256) void cvt_kernel(const float* __restrict__ in,
                                                  bf16* __restrict__ out, int n4) {
  int i = blockIdx.x * blockDim.x + threadIdx.x;
  if (i < n4) {
    float4 v = ((const float4*)in)[i];
    bf16x4 o = { (bf16)v.x, (bf16)v.y, (bf16)v.z, (bf16)v.w };
    ((bf16x4*)out)[i] = o;
  }
}

// ---------------- QKV GEMM (unchanged — R9/R10 proven) ----------------
__global__ __launch_bounds__(256, 3) void gemm_qkv(
    const bf16* __restrict__ A, const float* __restrict__ W,
    const float* __restrict__ bias,
    bf16* __restrict__ Qb, bf16* __restrict__ Kb, bf16* __restrict__ Vt)
{
  __shared__ bf16 lA[2][128 * 32];
  __shared__ bf16 lB[2][128 * 32];
  const int tid = threadIdx.x;
  const int wave = tid >> 6, lane = tid & 63;
  const int l15 = lane & 15, quad = lane >> 4;
  const int wm = wave >> 1, wn = wave & 1;
  const int tm = blockIdx.y * 128, tn = blockIdx.x * 128;

  f32x4 acc[4][4] = {};

  const int srow = tid >> 2, sch = (tid & 3) * 8;
  const bf16*  ga = &A[(size_t)(tm + srow) * DIMD + sch];
  const float* gb = &W[(size_t)(tn + srow) * DIMD + sch];

  g2l16(ga,                     &lA[0][wave * 512]);
  g2l16(ga + (size_t)64 * DIMD, &lA[0][2048 + wave * 512]);
  float4 bv0 = ((const float4*)gb)[0], bv1 = ((const float4*)gb)[1];
  float4 bv2 = ((const float4*)(gb + (size_t)64 * DIMD))[0],
         bv3 = ((const float4*)(gb + (size_t)64 * DIMD))[1];

  for (int kt = 0; kt < 32; kt++) {
    bf16* sB = lB[kt & 1];
    *(bf16x8*)&sB[srow * 32 + sch]        = cvt8(bv0, bv1);
    *(bf16x8*)&sB[(64 + srow) * 32 + sch] = cvt8(bv2, bv3);
    __syncthreads();

    if (kt < 31) {
      const int kn = (kt + 1) * 32;
      bf16* nA = lA[(kt + 1) & 1];
      g2l16(ga + kn,                     &nA[wave * 512]);
      g2l16(ga + kn + (size_t)64 * DIMD, &nA[2048 + wave * 512]);
      const float* gbn = gb + kn;
      bv0 = ((const float4*)gbn)[0]; bv1 = ((const float4*)gbn)[1];
      bv2 = ((const float4*)(gbn + (size_t)64 * DIMD))[0];
      bv3 = ((const float4*)(gbn + (size_t)64 * DIMD))[1];
    }

    const bf16* sA = lA[kt & 1];
    bf16x8 af[4], bfr[4];
#pragma unroll
    for (int i = 0; i < 4; i++)
      af[i] = *(const bf16x8*)&sA[(wm * 64 + i * 16 + l15) * 32 + quad * 8];
#pragma unroll
    for (int i = 0; i < 4; i++)
      bfr[i] = *(const bf16x8*)&sB[(wn * 64 + i * 16 + l15) * 32 + quad * 8];
#pragma unroll
    for (int i = 0; i < 4; i++)
#pragma unroll
      for (int j = 0; j < 4; j++)
        acc[i][j] = __builtin_amdgcn_mfma_f32_16x16x32_bf16(af[i], bfr[j], acc[i][j], 0, 0, 0);
  }

  const int sel = tn >> 10;  // 0=Q 1=K 2=V
#pragma unroll
  for (int j = 0; j < 4; j++) {
    const int n = tn + wn * 64 + j * 16 + l15;
    const float bv = bias[n];
    const int d = n & 1023, h = d >> 6, hd = d & 63;
#pragma unroll
    for (int i = 0; i < 4; i++) {
      const int mbase = tm + wm * 64 + i * 16 + quad * 4;
      const int b = mbase >> 11, s0 = mbase & 2047;
      const int bh = b * NHEAD + h;
      if (sel == 2) {
        bf16x4 vv = { (bf16)(acc[i][j][0] + bv), (bf16)(acc[i][j][1] + bv),
                      (bf16)(acc[i][j][2] + bv), (bf16)(acc[i][j][3] + bv) };
        *(bf16x4*)&Vt[((size_t)bh * HDIM + hd) * SEQ + s0] = vv;
      } else {
#pragma unroll
        for (int r = 0; r < 4; r++) {
          float v = acc[i][j][r] + bv;
          if (sel == 0)
            Qb[((size_t)bh * SEQ + s0 + r) * HDIM + hd] = (bf16)(v * 0.18033688f); // 0.125*log2e
          else
            Kb[((size_t)bh * SEQ + s0 + r) * HDIM + hd] = (bf16)v;
        }
      }
    }
  }
}

// ---------------- proj GEMM v2: both operands async via global_load_lds ----
__global__ __launch_bounds__(256, 2) void gemm_proj(
    const bf16* __restrict__ A, const bf16* __restrict__ Bt,
    const float* __restrict__ bias, float* __restrict__ out)
{
  __shared__ bf16 lA[2][64 * 32];
  __shared__ bf16 lB[2][128 * 32];
  const int tid = threadIdx.x;
  const int wave = tid >> 6, lane = tid & 63;
  const int l15 = lane & 15, quad = lane >> 4;
  const int tm = blockIdx.y * 64, tn = blockIdx.x * 128;

  f32x4 acc[4][2] = {};

  const int srow = tid >> 2, sch = (tid & 3) * 8;
  const bf16* ga = &A[(size_t)(tm + srow) * DIMD + sch];
  const bf16* gb = &Bt[(size_t)(tn + srow) * DIMD + sch];

  g2l16(ga,                     &lA[0][wave * 512]);
  g2l16(gb,                     &lB[0][wave * 512]);
  g2l16(gb + (size_t)64 * DIMD, &lB[0][2048 + wave * 512]);

  for (int kt = 0; kt < 32; kt++) {
    __syncthreads();

    if (kt < 31) {
      const int kn = (kt + 1) * 32;
      bf16* nA = lA[(kt + 1) & 1];
      bf16* nB = lB[(kt + 1) & 1];
      g2l16(ga + kn,                     &nA[wave * 512]);
      g2l16(gb + kn,                     &nB[wave * 512]);
      g2l16(gb + kn + (size_t)64 * DIMD, &nB[2048 + wave * 512]);
    }

    const bf16* sA = lA[kt & 1];
    const bf16* sB = lB[kt & 1];
    bf16x8 af[4], bfr[2];
#pragma unroll
    for (int i = 0; i < 4; i++)
      af[i] = *(const bf16x8*)&sA[(i * 16 + l15) * 32 + quad * 8];
#pragma unroll
    for (int j = 0; j < 2; j++)
      bfr[j] = *(const bf16x8*)&sB[(wave * 32 + j * 16 + l15) * 32 + quad * 8];
#pragma unroll
    for (int i = 0; i < 4; i++)
#pragma unroll
      for (int j = 0; j < 2; j++)
        acc[i][j] = __builtin_amdgcn_mfma_f32_16x16x32_bf16(af[i], bfr[j], acc[i][j], 0, 0, 0);
  }

#pragma unroll
  for (int j = 0; j < 2; j++) {
    const int n = tn + wave * 32 + j * 16 + l15;
    const float bv = bias[n];
#pragma unroll
    for (int i = 0; i < 4; i++) {
      const int mbase = tm + i * 16 + quad * 4;
#pragma unroll
      for (int r = 0; r < 4; r++)
        out[(size_t)(mbase + r) * DIMD + n] = acc[i][j][r] + bv;
    }
  }
}

// ---------------- flash attention v10: v6 structure + in-register P ----------
// Exact v6 (59.6us proven) with ONE change: P lives in registers across the
// iteration boundary instead of LDS. pack(s0,s1) -> pf[4] via bf16 pack +
// __shfl_xor(,32) half-exchange (hardware-validated by v9's passing run;
// v9's failure was KVBLK=128 register spill — WRITE_SIZE 142MB — not the
// exchange). Removes lP (-18.4KB LDS), 8 ds_write_b64 + 4 ds_read_b128 per
// wave-iter (DS volume -29%), and the 4-way-conflicting P-write pattern.
// pf layout check vs v6's lP consumption: pf[c] = src[4q..4q+3], q=2(c&1)+h,
// src = (c<2)?s0:s1, lo half from h'=0 lane, hi half from h'=1 lane.
#define LSTR 72
__global__ __launch_bounds__(256, 2) void attn_kernel(
    const bf16* __restrict__ Qb, const bf16* __restrict__ Kb,
    const bf16* __restrict__ Vt, bf16* __restrict__ Ob)
{
  __shared__ bf16 lKV[2][2][64 * LSTR];   // [buf][K=0/V=1]

  const int tid = threadIdx.x;
  const int wave = tid >> 6, lane = tid & 63;
  const int l31 = lane & 31, h = lane >> 5;
  const int xcd = blockIdx.x & 7, grp = blockIdx.x >> 3;
  const int bh = xcd + 8 * (grp & 3);
  const int qt = grp >> 2;

  const int qrow = qt * 128 + wave * 32 + l31;
  const bf16* qp = Qb + ((size_t)bh * SEQ + qrow) * HDIM + h * 8;
  bf16x8 qf[4];
#pragma unroll
  for (int c = 0; c < 4; c++) qf[c] = *(const bf16x8*)(qp + c * 16);

  const int srow = tid >> 3;            // 0..31
  const int sch = (tid & 7) * 8;        // bf16 elem offset in 64
  const bf16* kg = Kb + ((size_t)bh * SEQ + srow) * HDIM + sch;
  const bf16* vg = Vt + ((size_t)bh * HDIM + srow) * SEQ + sch;

  uint4 kr0 = *(const uint4*)(kg);
  uint4 kr1 = *(const uint4*)(kg + 32 * HDIM);
  uint4 vr0 = *(const uint4*)(vg);
  uint4 vr1 = *(const uint4*)(vg + 32 * SEQ);

  bf16x8 pf[4];   // packed P(t-1), replaces lP

  f32x16 o0 = {}, o1 = {};
  float mrow = -1e30f, lrow = 0.f;

  for (int kt = 0; kt < SEQ / 64; kt++) {
    bf16* sK = lKV[kt & 1][0];
    bf16* sV = lKV[kt & 1][1];
    *(uint4*)&sK[srow * LSTR + sch]        = kr0;
    *(uint4*)&sK[(32 + srow) * LSTR + sch] = kr1;
    *(uint4*)&sV[srow * LSTR + sch]        = vr0;
    *(uint4*)&sV[(32 + srow) * LSTR + sch] = vr1;
    __syncthreads();

    const int ktn = (kt + 1) & (SEQ / 64 - 1);
    kr0 = *(const uint4*)(kg + (size_t)ktn * 64 * HDIM);
    kr1 = *(const uint4*)(kg + (size_t)ktn * 64 * HDIM + 32 * HDIM);
    vr0 = *(const uint4*)(vg + ktn * 64);
    vr1 = *(const uint4*)(vg + ktn * 64 + 32 * SEQ);

    // S^T(t) = K Q^T : issue first so softmax's dependency is in flight
    f32x16 s0 = {}, s1 = {};
#pragma unroll
    for (int c = 0; c < 4; c++) {
      bf16x8 k0 = *(const bf16x8*)&sK[l31 * LSTR + c * 16 + h * 8];
      bf16x8 k1 = *(const bf16x8*)&sK[(32 + l31) * LSTR + c * 16 + h * 8];
      s0 = __builtin_amdgcn_mfma_f32_32x32x16_bf16(k0, qf[c], s0, 0, 0, 0);
      s1 = __builtin_amdgcn_mfma_f32_32x32x16_bf16(k1, qf[c], s1, 0, 0, 0);
    }

    // PV(t-1): P in pf regs, V(t-1) in the OTHER KV buffer.
    if (kt > 0) {
      const bf16* pV = lKV[(kt + 1) & 1][1];
#pragma unroll
      for (int c = 0; c < 4; c++) {
        bf16x8 v0 = *(const bf16x8*)&pV[l31 * LSTR + c * 16 + h * 8];
        bf16x8 v1 = *(const bf16x8*)&pV[(32 + l31) * LSTR + c * 16 + h * 8];
        o0 = __builtin_amdgcn_mfma_f32_32x32x16_bf16(v0, pf[c], o0, 0, 0, 0);
        o1 = __builtin_amdgcn_mfma_f32_32x32x16_bf16(v1, pf[c], o1, 0, 0, 0);
      }
    }

    // softmax(t) — v6's exact serial-chain form (v8 proved trees don't help)
    float mx = -1e30f;
#pragma unroll
    for (int r = 0; r < 16; r++) { mx = fmaxf(mx, s0[r]); mx = fmaxf(mx, s1[r]); }
    mx = fmaxf(mx, __shfl_xor(mx, 32, 64));
    const float nm = fmaxf(mrow, mx);
    const float alpha = EXP2F(mrow - nm);
    mrow = nm;

    float rs = 0.f;
#pragma unroll
    for (int r = 0; r < 16; r++) {
      const float p0 = EXP2F(s0[r] - nm);
      const float p1 = EXP2F(s1[r] - nm);
      s0[r] = p0; s1[r] = p1;
      rs += p0 + p1;
    }
    rs += __shfl_xor(rs, 32, 64);
    lrow = lrow * alpha + rs;

    // o-rescale: must follow PV(t-1) completion (reg dependency enforces)
#pragma unroll
    for (int r = 0; r < 16; r++) { o0[r] *= alpha; o1[r] *= alpha; }

    // pack P(t) -> pf regs via half-exchange (replaces lP write/read)
#pragma unroll
    for (int g = 0; g < 2; g++) {
      const f32x16& sg = (g == 0) ? s0 : s1;
#pragma unroll
      for (int cp = 0; cp < 2; cp++) {
        bf16x4 pk0 = { (bf16)sg[8 * cp + 0], (bf16)sg[8 * cp + 1],
                       (bf16)sg[8 * cp + 2], (bf16)sg[8 * cp + 3] };   // q=2cp
        bf16x4 pk1 = { (bf16)sg[8 * cp + 4], (bf16)sg[8 * cp + 5],
                       (bf16)sg[8 * cp + 6], (bf16)sg[8 * cp + 7] };   // q=2cp+1
        uint2 w0 = *(uint2*)&pk0;
        uint2 w1 = *(uint2*)&pk1;
        unsigned send0 = h ? w0.x : w1.x;
        unsigned send1 = h ? w0.y : w1.y;
        unsigned recv0 = __shfl_xor(send0, 32, 64);
        unsigned recv1 = __shfl_xor(send1, 32, 64);
        union { unsigned u[4]; bf16x8 v; } f;
        f.u[0] = h ? recv0 : w0.x;   // j0j1  (h'=0 source)
        f.u[1] = h ? recv1 : w0.y;   // j2j3
        f.u[2] = h ? w1.x : recv0;   // j4j5  (h'=1 source)
        f.u[3] = h ? w1.y : recv1;   // j6j7
        pf[2 * g + cp] = f.v;
      }
    }
  }

  // drain: PV(31) from buf[31&1 = 1], P in pf regs
  {
    const bf16* pV = lKV[1][1];
#pragma unroll
    for (int c = 0; c < 4; c++) {
      bf16x8 v0 = *(const bf16x8*)&pV[l31 * LSTR + c * 16 + h * 8];
      bf16x8 v1 = *(const bf16x8*)&pV[(32 + l31) * LSTR + c * 16 + h * 8];
      o0 = __builtin_amdgcn_mfma_f32_32x32x16_bf16(v0, pf[c], o0, 0, 0, 0);
      o1 = __builtin_amdgcn_mfma_f32_32x32x16_bf16(v1, pf[c], o1, 0, 0, 0);
    }
  }

  const int b = bh >> 4, head = bh & 15;
  const float inv = 1.f / lrow;
  const size_t base = ((size_t)b * SEQ + qrow) * DIMD + head * HDIM;
#pragma unroll
  for (int g = 0; g < 4; g++) {
    bf16x4 oa = { (bf16)(o0[4*g] * inv), (bf16)(o0[4*g+1] * inv),
                  (bf16)(o0[4*g+2] * inv), (bf16)(o0[4*g+3] * inv) };
    bf16x4 ob = { (bf16)(o1[4*g] * inv), (bf16)(o1[4*g+1] * inv),
                  (bf16)(o1[4*g+2] * inv), (bf16)(o1[4*g+3] * inv) };
    *(bf16x4*)&Ob[base + g * 8 + h * 4]      = oa;
    *(bf16x4*)&Ob[base + 32 + g * 8 + h * 4] = ob;
  }
}

extern "C" void kernel_launch(void* const* d_in, const int* in_sizes, int n_in,
                              void* d_out, int out_size, void* d_ws, size_t ws_size,
                              hipStream_t stream) {
  const float* x      = (const float*)d_in[0];
  const float* w_qkv  = (const float*)d_in[1];
  const float* b_qkv  = (const float*)d_in[2];
  const float* w_proj = (const float*)d_in[3];
  const float* b_proj = (const float*)d_in[4];
  float* out = (float*)d_out;
  char* ws = (char*)d_ws;

  bf16* Qb = (bf16*)d_out;
  bf16* Kb = (bf16*)d_out + (size_t)MTOT * DIMD;
  bf16* xb     = (bf16*)(ws + OFF_XB);
  bf16* Ob     = (bf16*)(ws + OFF_OB);   // overlays xb (dead after QKV GEMM)
  bf16* Vt     = (bf16*)(ws + OFF_VT);
  bf16* wprojb = (bf16*)(ws + OFF_WP);   // overlays Vt (dead after attn)

  cvt_kernel<<<(MTOT * DIMD / 4) / 256, 256, 0, stream>>>(x, xb, MTOT * DIMD / 4);
  gemm_qkv<<<dim3(24, 32), 256, 0, stream>>>(xb, w_qkv, b_qkv, Qb, Kb, Vt);
  attn_kernel<<<BATCH * NHEAD * (SEQ / 128), 256, 0, stream>>>(Qb, Kb, Vt, Ob);
  cvt_kernel<<<(DIMD * DIMD / 4) / 256, 256, 0, stream>>>(w_proj, wprojb, DIMD * DIMD / 4);
  gemm_proj<<<dim3(8, 64), 256, 0, stream>>>(Ob, wprojb, b_proj, out);
}